// Round 7
// baseline (420.837 us; speedup 1.0000x reference)
//
#include <hip/hip_runtime.h>

typedef __attribute__((ext_vector_type(8))) __bf16 bf16x8;
typedef __attribute__((ext_vector_type(4))) __bf16 bf16x4;
typedef __attribute__((ext_vector_type(2))) __bf16 bf16x2;
typedef __attribute__((ext_vector_type(4))) float f32x4;

#define LOG2E 1.44269504088896f
#define KSWZ(t) (((t) & 7) << 4)
#define VSWZ(d) ((((d) & 7) ^ (((d) >> 3) & 7)) << 4)

// 28 instances of dilated causal attention, each L=2048, d=64.
// q/k/v: (1, 8192, 12, 64) fp32 -> elem = tok*768 + head*64 + d.
// QBLK=128 (8 waves x 16 q-rows), KV tile 64, chunks of <=8 KV tiles:
// 40 units/inst -> 1120 blocks, XCD-chunked, heavy-first.
// Wave-specialized staging (waves 0-3: K, 4-7: V^T), swapped QK^T ->
// in-register softmax, defer-max (THR=8, log2 domain).
// FUSED epilogue: qt<4 writes out directly; qt>=4 writes ws slot then
// last-arriving chunk (atomic counter) merges in-kernel. Output zeroing
// for non-dilated rows is fused into the epilogues (no big memset).
// ws slot: 8448 floats = O[128][64] + m[128] + l[128]; slot = inst*36 + b + c.
// counters: 28*16 ints at top of ws (ws_size - 4K, 256B aligned).

__device__ __forceinline__ void inst_decode(int inst, int& head, int& sstart,
                                            int& r, int& off)
{
    if (inst < 16)      { head = inst & 3;          sstart = (inst >> 2) * 2048; r = 1; off = 0; }
    else if (inst < 24) { int j = inst - 16; head = 4 + (j & 3); sstart = (j >> 2) * 4096; r = 2; off = 1; }
    else                { head = 8 + (inst - 24);   sstart = 0;                  r = 4; off = 2; }
}

__global__ __launch_bounds__(512)
void dilattn_fused(const float* __restrict__ Qg, const float* __restrict__ Kg,
                   const float* __restrict__ Vg, float* __restrict__ Og,
                   float* __restrict__ ws, int* __restrict__ cnt,
                   const int* __restrict__ causal_p)
{
    const int bid  = blockIdx.x;
    const int unit = (bid & 7) * 140 + (bid >> 3);   // XCD-contiguous units
    const int inst = unit / 40;
    const int u    = 39 - (unit % 40);               // heavy chunks first
    int qt, c;
    if (u < 4) { qt = u; c = 0; }
    else {
        int v = u - 4;
        if (v < 8)       { qt = 4 + (v >> 1); c = v & 1; }
        else if (v < 20) { int t = v - 8; int q3 = t / 3; qt = 8 + q3; c = t - 3 * q3; }
        else             { int t = v - 20; qt = 12 + (t >> 2); c = t & 3; }
    }
    int head, sstart, r, off;
    inst_decode(inst, head, sstart, r, off);

    const int causal = *causal_p;
    int kt_begin, kt_end;
    bool direct;
    if (causal) {
        int nkt = 2 * qt + 2;
        kt_begin = c * 8;
        kt_end   = (kt_begin + 8 < nkt) ? kt_begin + 8 : nkt;
        direct   = (qt < 4);
    } else {
        if (c) return;
        kt_begin = 0; kt_end = 32; direct = true;
    }

    const int tid  = threadIdx.x;
    const int lane = tid & 63;
    const int wave = tid >> 6;                 // 0..7
    const int l15  = lane & 15;
    const int lhi  = lane >> 4;

    __shared__ char KV[2][16384];              // per buf: K 8K | V^T 8K
    __shared__ __bf16 P_lds[8][16 * 64];       // per-wave P bridge (swizzled)
    __shared__ int s_last;

    // ---- Q fragments (scale * log2e folded in); serves as MFMA B ----
    const int qrow_base = qt * 128 + wave * 16;
    const float qscale = 0.125f * LOG2E;
    bf16x8 qfrag[2];
    {
        int qr = qrow_base + l15;
        long qtok = sstart + off + (long)r * qr;
        const float* qp = Qg + qtok * 768 + head * 64 + lhi * 8;
#pragma unroll
        for (int dc = 0; dc < 2; dc++) {
            f32x4 a = *(const f32x4*)(qp + dc * 32);
            f32x4 b = *(const f32x4*)(qp + dc * 32 + 4);
#pragma unroll
            for (int j = 0; j < 4; j++) {
                qfrag[dc][j]     = (__bf16)(a[j] * qscale);
                qfrag[dc][4 + j] = (__bf16)(b[j] * qscale);
            }
        }
    }

    f32x4 acc[4] = {};                          // O: row q=lhi*4+reg, col d=dt*16+l15
    float m_run = -INFINITY;                    // per-lane: q = l15
    float l_run = 0.f;

    // ---- wave-specialized staging roles ----
    const bool isK = (wave < 4);
    const int t2   = tid & 255;
    const int tokK = t2 >> 2, q4 = t2 & 3;          // K: (token, d-quarter)
    const int tokP = t2 >> 3, d8 = (t2 & 7) * 8;    // V: (token-pair, 8 d)

    f32x4 r0, r1, r2, r3;                       // staging regs (next tile)

#define LOAD_TILE(KT) do {                                                     \
        long tb = sstart + off + (long)r * ((KT) * 64);                        \
        if (isK) {                                                             \
            const float* p_ = Kg + (tb + (long)r * tokK) * 768 + head * 64 + q4 * 16; \
            r0 = *(const f32x4*)(p_);      r1 = *(const f32x4*)(p_ + 4);       \
            r2 = *(const f32x4*)(p_ + 8);  r3 = *(const f32x4*)(p_ + 12);      \
        } else {                                                               \
            const float* p0_ = Vg + (tb + (long)r * 2 * tokP) * 768 + head * 64 + d8; \
            const float* p1_ = p0_ + (long)r * 768;                            \
            r0 = *(const f32x4*)(p0_);     r1 = *(const f32x4*)(p0_ + 4);      \
            r2 = *(const f32x4*)(p1_);     r3 = *(const f32x4*)(p1_ + 4);      \
        }                                                                      \
    } while (0)

#define STORE_TILE(BUFI) do {                                                  \
        if (isK) {                                                             \
            char* Kb_ = KV[(BUFI)];                                            \
            bf16x8 w0_, w1_;                                                   \
            _Pragma("unroll")                                                  \
            for (int j = 0; j < 4; j++) {                                      \
                w0_[j] = (__bf16)r0[j]; w0_[4 + j] = (__bf16)r1[j];            \
                w1_[j] = (__bf16)r2[j]; w1_[4 + j] = (__bf16)r3[j];            \
            }                                                                  \
            int kb_ = tokK * 128 + q4 * 32;                                    \
            *(bf16x8*)(Kb_ + ((kb_)      ^ KSWZ(tokK))) = w0_;                 \
            *(bf16x8*)(Kb_ + ((kb_ + 16) ^ KSWZ(tokK))) = w1_;                 \
        } else {                                                               \
            char* Vb_ = KV[(BUFI)] + 8192;                                     \
            _Pragma("unroll")                                                  \
            for (int j = 0; j < 4; j++) {                                      \
                int d_ = d8 + j;                                               \
                bf16x2 wa_; wa_[0] = (__bf16)r0[j]; wa_[1] = (__bf16)r2[j];    \
                *(bf16x2*)(Vb_ + ((d_ * 128 + tokP * 4) ^ VSWZ(d_))) = wa_;    \
                int d2_ = d8 + 4 + j;                                          \
                bf16x2 wb_; wb_[0] = (__bf16)r1[j]; wb_[1] = (__bf16)r3[j];    \
                *(bf16x2*)(Vb_ + ((d2_ * 128 + tokP * 4) ^ VSWZ(d2_))) = wb_;  \
            }                                                                  \
        }                                                                      \
    } while (0)

    // ---- prologue: stage first tile ----
    LOAD_TILE(kt_begin);
    STORE_TILE(0);
    __syncthreads();

    int bufi = 0;
    for (int kt = kt_begin; kt < kt_end; kt++) {
        const bool pf = (kt + 1 < kt_end);
        if (pf) LOAD_TILE(kt + 1);             // issue early; lands under compute

        char* Kb = KV[bufi];
        char* Vb = KV[bufi] + 8192;

        // ---- S' = K Q^T : lane owns q = l15; regs (nt,reg) = k values ----
        f32x4 s[4];
        __builtin_amdgcn_s_setprio(1);
#pragma unroll
        for (int nt = 0; nt < 4; nt++) {
            f32x4 cc = {};
#pragma unroll
            for (int dc = 0; dc < 2; dc++) {
                int krow = nt * 16 + l15;
                const bf16x8 kf = *(const bf16x8*)(Kb +
                    ((krow * 128 + dc * 64 + lhi * 16) ^ KSWZ(krow)));
                cc = __builtin_amdgcn_mfma_f32_16x16x32_bf16(kf, qfrag[dc], cc, 0, 0, 0);
            }
            s[nt] = cc;
        }
        __builtin_amdgcn_s_setprio(0);

        // ---- causal mask: tiles kt = 2qt, 2qt+1 overlap the diagonal ----
        if (causal && (kt >> 1) == qt) {
            const int kofs = kt * 64 - qt * 128 - wave * 16;  // k_local - q base
#pragma unroll
            for (int nt = 0; nt < 4; nt++)
#pragma unroll
                for (int reg = 0; reg < 4; reg++)
                    if (kofs + nt * 16 + lhi * 4 + reg > l15)
                        s[nt][reg] = -INFINITY;
        }

        // ---- in-register online softmax with defer-max (THR=8, log2) ----
        float mt = fmaxf(fmaxf(s[0][0], s[0][1]), fmaxf(s[0][2], s[0][3]));
#pragma unroll
        for (int nt = 1; nt < 4; nt++)
            mt = fmaxf(mt, fmaxf(fmaxf(s[nt][0], s[nt][1]), fmaxf(s[nt][2], s[nt][3])));
        mt = fmaxf(mt, __shfl_xor(mt, 16));
        mt = fmaxf(mt, __shfl_xor(mt, 32));
        if (!__all(mt - m_run <= 8.0f)) {
            float mn = fmaxf(m_run, mt);
            float sc = exp2f(m_run - mn);
            l_run *= sc;
            float scr[4];
#pragma unroll
            for (int reg = 0; reg < 4; reg++) scr[reg] = __shfl(sc, lhi * 4 + reg);
#pragma unroll
            for (int dt = 0; dt < 4; dt++)
#pragma unroll
                for (int reg = 0; reg < 4; reg++) acc[dt][reg] *= scr[reg];
            m_run = mn;
        }
        float ps = 0.f;
#pragma unroll
        for (int nt = 0; nt < 4; nt++)
#pragma unroll
            for (int reg = 0; reg < 4; reg++) {
                float p = exp2f(s[nt][reg] - m_run);
                s[nt][reg] = p;
                ps += p;
            }
        ps += __shfl_xor(ps, 16);
        ps += __shfl_xor(ps, 32);
        l_run += ps;

        // ---- P -> wave-private LDS bridge: 4 consecutive k per write ----
        char* pl = (char*)P_lds[wave];
        const int rs = (l15 & 7) << 4;
#pragma unroll
        for (int nt = 0; nt < 4; nt++) {
            bf16x4 pw;
#pragma unroll
            for (int reg = 0; reg < 4; reg++) pw[reg] = (__bf16)s[nt][reg];
            *(bf16x4*)(pl + ((l15 * 128 + (nt * 16 + lhi * 4) * 2) ^ rs)) = pw;
        }

        // ---- O += P V ----
        __builtin_amdgcn_s_setprio(1);
#pragma unroll
        for (int kc = 0; kc < 2; kc++) {
            const bf16x8 pfg = *(const bf16x8*)(pl +
                ((l15 * 128 + kc * 64 + lhi * 16) ^ rs));
#pragma unroll
            for (int dt = 0; dt < 4; dt++) {
                int drow = dt * 16 + l15;
                const bf16x8 vf = *(const bf16x8*)(Vb +
                    ((drow * 128 + kc * 64 + lhi * 16) ^ VSWZ(drow)));
                acc[dt] = __builtin_amdgcn_mfma_f32_16x16x32_bf16(pfg, vf, acc[dt], 0, 0, 0);
            }
        }
        __builtin_amdgcn_s_setprio(0);

        if (pf) STORE_TILE(bufi ^ 1);          // publish next tile
        __syncthreads();
        bufi ^= 1;
    }

    if (direct) {
        // ---- normalize + scatter + fused zero rows ----
        float lq[4];
#pragma unroll
        for (int reg = 0; reg < 4; reg++) lq[reg] = __shfl(l_run, lhi * 4 + reg);
#pragma unroll
        for (int reg = 0; reg < 4; reg++) {
            float inv = 1.0f / lq[reg];
            int qr = qrow_base + lhi * 4 + reg;
            long tok = sstart + off + (long)r * qr;
            float* op = Og + tok * 768 + head * 64 + l15;
#pragma unroll
            for (int dt = 0; dt < 4; dt++) op[dt * 16] = acc[dt][reg] * inv;
            if (r >= 2) {
                float* z1 = op - 768;
#pragma unroll
                for (int dt = 0; dt < 4; dt++) z1[dt * 16] = 0.f;
            }
            if (r == 4) {
                float* z2 = op - 2 * 768;
                float* z3 = op + 768;
#pragma unroll
                for (int dt = 0; dt < 4; dt++) { z2[dt * 16] = 0.f; z3[dt * 16] = 0.f; }
            }
        }
        return;
    }

    // ---- write unnormalized partial to ws slot ----
    const int nc = (2 * qt + 9) >> 3;          // chunks for this qt: 2..4
    const int b  = (qt < 8)  ? (qt - 4) * 2
                 : (qt < 12) ? 8 + (qt - 8) * 3
                 :             20 + (qt - 12) * 4;
    float* slotp = ws + (size_t)(inst * 36 + b + c) * 8448;
#pragma unroll
    for (int reg = 0; reg < 4; reg++) {
        int row = wave * 16 + lhi * 4 + reg;
        float* op = slotp + row * 64 + l15;
#pragma unroll
        for (int dt = 0; dt < 4; dt++) op[dt * 16] = acc[dt][reg];
    }
    if (lhi == 0) {                             // lane owns q = l15
        slotp[8192 + wave * 16 + l15] = m_run;
        slotp[8320 + wave * 16 + l15] = l_run;
    }

    // ---- last-arriving chunk merges ----
    __threadfence();
    __syncthreads();
    if (tid == 0) {
        int old = atomicAdd(&cnt[inst * 16 + qt], 1);
        s_last = (old == nc - 1);
    }
    __syncthreads();
    if (!s_last) return;
    __threadfence();

    const float* base = ws + (size_t)(inst * 36 + b) * 8448;
    const int row = tid >> 2;                  // 0..127
    const int c16 = (tid & 3) * 16;

    float mv[4], lv[4];
    float m = -INFINITY;
#pragma unroll
    for (int cc = 0; cc < 4; cc++) {
        if (cc < nc) {
            mv[cc] = base[cc * 8448 + 8192 + row];
            lv[cc] = base[cc * 8448 + 8320 + row];
            m = fmaxf(m, mv[cc]);
        }
    }
    float w[4];
    float L = 0.f;
#pragma unroll
    for (int cc = 0; cc < 4; cc++) {
        if (cc < nc) {
            w[cc] = exp2f(mv[cc] - m);
            L += w[cc] * lv[cc];
        }
    }
    const float invL = 1.0f / L;

    f32x4 o[4] = {};
#pragma unroll
    for (int cc = 0; cc < 4; cc++) {
        if (cc < nc) {
            const float* op = base + cc * 8448 + row * 64 + c16;
#pragma unroll
            for (int j = 0; j < 4; j++) {
                f32x4 t = *(const f32x4*)(op + j * 4);
#pragma unroll
                for (int e = 0; e < 4; e++) o[j][e] += w[cc] * t[e];
            }
        }
    }

    long tok = sstart + off + (long)r * (qt * 128 + row);
    float* og = Og + tok * 768 + head * 64 + c16;
#pragma unroll
    for (int j = 0; j < 4; j++) {
        f32x4 t;
#pragma unroll
        for (int e = 0; e < 4; e++) t[e] = o[j][e] * invL;
        *(f32x4*)(og + j * 4) = t;
    }
    // ---- fused zero rows for non-dilated tokens ----
    const f32x4 zz = {};
    if (r >= 2) {
        float* z1 = og - 768;
#pragma unroll
        for (int j = 0; j < 4; j++) *(f32x4*)(z1 + j * 4) = zz;
    }
    if (r == 4) {
        float* z2 = og - 2 * 768;
        float* z3 = og + 768;
#pragma unroll
        for (int j = 0; j < 4; j++) { *(f32x4*)(z2 + j * 4) = zz; *(f32x4*)(z3 + j * 4) = zz; }
    }
#undef LOAD_TILE
#undef STORE_TILE
}

extern "C" void kernel_launch(void* const* d_in, const int* in_sizes, int n_in,
                              void* d_out, int out_size, void* d_ws, size_t ws_size,
                              hipStream_t stream)
{
    const float* q = (const float*)d_in[0];
    const float* k = (const float*)d_in[1];
    const float* v = (const float*)d_in[2];
    const int* causal = (const int*)d_in[3];
    float* out = (float*)d_out;
    float* ws  = (float*)d_ws;

    // per-(inst,qt) chunk counters at top of ws, zeroed every call
    size_t cnt_off = (ws_size - 4096) & ~(size_t)255;
    int* cnt = (int*)((char*)d_ws + cnt_off);
    hipMemsetAsync(cnt, 0, 28 * 16 * sizeof(int), stream);

    dilattn_fused<<<dim3(28 * 40), dim3(512), 0, stream>>>(q, k, v, out, ws, cnt, causal);
}

// Round 8
// 69.553 us; speedup vs baseline: 6.0506x; 6.0506x over previous
//
#include <hip/hip_runtime.h>

typedef __attribute__((ext_vector_type(8))) __bf16 bf16x8;
typedef __attribute__((ext_vector_type(4))) __bf16 bf16x4;
typedef __attribute__((ext_vector_type(2))) __bf16 bf16x2;
typedef __attribute__((ext_vector_type(4))) float f32x4;

#define LOG2E 1.44269504088896f
#define KSWZ(t) (((t) & 7) << 4)
#define VSWZ(d) ((((d) & 7) ^ (((d) >> 3) & 7)) << 4)

// 28 instances of dilated causal attention, each L=2048, d=64.
// q/k/v: (1, 8192, 12, 64) fp32 -> elem = tok*768 + head*64 + d.
// QBLK=128 (8 waves x 16 q-rows), KV tile 64, chunks of <=8 KV tiles:
// 40 units/inst -> 1120 blocks, XCD-chunked, heavy-first.
// Wave-specialized staging (waves 0-3: K, 4-7: V^T), swapped QK^T ->
// in-register softmax, defer-max (THR=8, log2 domain).
// Two kernels (NO device fences — R7 lesson: in-kernel cross-XCD fences
// stall the grid ~7x; kernel boundary gives visibility for free).
// Output zeroing for non-dilated rows fused into epilogues (no big memset).
// ws slot (17408 B): O[128][64] bf16 (16384) + m[128] f32 + l[128] f32.
// slot index = inst*36 + b + c.

__device__ __forceinline__ void inst_decode(int inst, int& head, int& sstart,
                                            int& r, int& off)
{
    if (inst < 16)      { head = inst & 3;          sstart = (inst >> 2) * 2048; r = 1; off = 0; }
    else if (inst < 24) { int j = inst - 16; head = 4 + (j & 3); sstart = (j >> 2) * 4096; r = 2; off = 1; }
    else                { head = 8 + (inst - 24);   sstart = 0;                  r = 4; off = 2; }
}

__global__ __launch_bounds__(512)
void dilattn_partial(const float* __restrict__ Qg, const float* __restrict__ Kg,
                     const float* __restrict__ Vg, float* __restrict__ Og,
                     char* __restrict__ ws, const int* __restrict__ causal_p)
{
    const int bid  = blockIdx.x;
    const int unit = (bid & 7) * 140 + (bid >> 3);   // XCD-contiguous units
    const int inst = unit / 40;
    const int u    = 39 - (unit % 40);               // heavy chunks first
    int qt, c;
    if (u < 4) { qt = u; c = 0; }
    else {
        int v = u - 4;
        if (v < 8)       { qt = 4 + (v >> 1); c = v & 1; }
        else if (v < 20) { int t = v - 8; int q3 = t / 3; qt = 8 + q3; c = t - 3 * q3; }
        else             { int t = v - 20; qt = 12 + (t >> 2); c = t & 3; }
    }
    int head, sstart, r, off;
    inst_decode(inst, head, sstart, r, off);

    const int causal = *causal_p;
    int kt_begin, kt_end;
    bool direct;
    if (causal) {
        int nkt = 2 * qt + 2;
        kt_begin = c * 8;
        kt_end   = (kt_begin + 8 < nkt) ? kt_begin + 8 : nkt;
        direct   = (qt < 4);
    } else {
        if (c) return;
        kt_begin = 0; kt_end = 32; direct = true;
    }

    const int tid  = threadIdx.x;
    const int lane = tid & 63;
    const int wave = tid >> 6;                 // 0..7
    const int l15  = lane & 15;
    const int lhi  = lane >> 4;

    __shared__ char KV[2][16384];              // per buf: K 8K | V^T 8K
    __shared__ __bf16 P_lds[8][16 * 64];       // per-wave P bridge (swizzled)

    // ---- Q fragments (scale * log2e folded in); serves as MFMA B ----
    const int qrow_base = qt * 128 + wave * 16;
    const float qscale = 0.125f * LOG2E;
    bf16x8 qfrag[2];
    {
        int qr = qrow_base + l15;
        long qtok = sstart + off + (long)r * qr;
        const float* qp = Qg + qtok * 768 + head * 64 + lhi * 8;
#pragma unroll
        for (int dc = 0; dc < 2; dc++) {
            f32x4 a = *(const f32x4*)(qp + dc * 32);
            f32x4 b = *(const f32x4*)(qp + dc * 32 + 4);
#pragma unroll
            for (int j = 0; j < 4; j++) {
                qfrag[dc][j]     = (__bf16)(a[j] * qscale);
                qfrag[dc][4 + j] = (__bf16)(b[j] * qscale);
            }
        }
    }

    f32x4 acc[4] = {};                          // O: row q=lhi*4+reg, col d=dt*16+l15
    float m_run = -INFINITY;                    // per-lane: q = l15
    float l_run = 0.f;

    // ---- wave-specialized staging roles ----
    const bool isK = (wave < 4);
    const int t2   = tid & 255;
    const int tokK = t2 >> 2, q4 = t2 & 3;          // K: (token, d-quarter)
    const int tokP = t2 >> 3, d8 = (t2 & 7) * 8;    // V: (token-pair, 8 d)

    f32x4 r0, r1, r2, r3;                       // staging regs (next tile)

#define LOAD_TILE(KT) do {                                                     \
        long tb = sstart + off + (long)r * ((KT) * 64);                        \
        if (isK) {                                                             \
            const float* p_ = Kg + (tb + (long)r * tokK) * 768 + head * 64 + q4 * 16; \
            r0 = *(const f32x4*)(p_);      r1 = *(const f32x4*)(p_ + 4);       \
            r2 = *(const f32x4*)(p_ + 8);  r3 = *(const f32x4*)(p_ + 12);      \
        } else {                                                               \
            const float* p0_ = Vg + (tb + (long)r * 2 * tokP) * 768 + head * 64 + d8; \
            const float* p1_ = p0_ + (long)r * 768;                            \
            r0 = *(const f32x4*)(p0_);     r1 = *(const f32x4*)(p0_ + 4);      \
            r2 = *(const f32x4*)(p1_);     r3 = *(const f32x4*)(p1_ + 4);      \
        }                                                                      \
    } while (0)

#define STORE_TILE(BUFI) do {                                                  \
        if (isK) {                                                             \
            char* Kb_ = KV[(BUFI)];                                            \
            bf16x8 w0_, w1_;                                                   \
            _Pragma("unroll")                                                  \
            for (int j = 0; j < 4; j++) {                                      \
                w0_[j] = (__bf16)r0[j]; w0_[4 + j] = (__bf16)r1[j];            \
                w1_[j] = (__bf16)r2[j]; w1_[4 + j] = (__bf16)r3[j];            \
            }                                                                  \
            int kb_ = tokK * 128 + q4 * 32;                                    \
            *(bf16x8*)(Kb_ + ((kb_)      ^ KSWZ(tokK))) = w0_;                 \
            *(bf16x8*)(Kb_ + ((kb_ + 16) ^ KSWZ(tokK))) = w1_;                 \
        } else {                                                               \
            char* Vb_ = KV[(BUFI)] + 8192;                                     \
            _Pragma("unroll")                                                  \
            for (int j = 0; j < 4; j++) {                                      \
                int d_ = d8 + j;                                               \
                bf16x2 wa_; wa_[0] = (__bf16)r0[j]; wa_[1] = (__bf16)r2[j];    \
                *(bf16x2*)(Vb_ + ((d_ * 128 + tokP * 4) ^ VSWZ(d_))) = wa_;    \
                int d2_ = d8 + 4 + j;                                          \
                bf16x2 wb_; wb_[0] = (__bf16)r1[j]; wb_[1] = (__bf16)r3[j];    \
                *(bf16x2*)(Vb_ + ((d2_ * 128 + tokP * 4) ^ VSWZ(d2_))) = wb_;  \
            }                                                                  \
        }                                                                      \
    } while (0)

    // ---- prologue: stage first tile ----
    LOAD_TILE(kt_begin);
    STORE_TILE(0);
    __syncthreads();

    int bufi = 0;
    for (int kt = kt_begin; kt < kt_end; kt++) {
        const bool pf = (kt + 1 < kt_end);
        if (pf) LOAD_TILE(kt + 1);             // issue early; lands under compute

        char* Kb = KV[bufi];
        char* Vb = KV[bufi] + 8192;

        // ---- S' = K Q^T : lane owns q = l15; regs (nt,reg) = k values ----
        f32x4 s[4];
        __builtin_amdgcn_s_setprio(1);
#pragma unroll
        for (int nt = 0; nt < 4; nt++) {
            f32x4 cc = {};
#pragma unroll
            for (int dc = 0; dc < 2; dc++) {
                int krow = nt * 16 + l15;
                const bf16x8 kf = *(const bf16x8*)(Kb +
                    ((krow * 128 + dc * 64 + lhi * 16) ^ KSWZ(krow)));
                cc = __builtin_amdgcn_mfma_f32_16x16x32_bf16(kf, qfrag[dc], cc, 0, 0, 0);
            }
            s[nt] = cc;
        }
        __builtin_amdgcn_s_setprio(0);

        // ---- causal mask: tiles kt = 2qt, 2qt+1 overlap the diagonal ----
        if (causal && (kt >> 1) == qt) {
            const int kofs = kt * 64 - qt * 128 - wave * 16;  // k_local - q base
#pragma unroll
            for (int nt = 0; nt < 4; nt++)
#pragma unroll
                for (int reg = 0; reg < 4; reg++)
                    if (kofs + nt * 16 + lhi * 4 + reg > l15)
                        s[nt][reg] = -INFINITY;
        }

        // ---- in-register online softmax with defer-max (THR=8, log2) ----
        float mt = fmaxf(fmaxf(s[0][0], s[0][1]), fmaxf(s[0][2], s[0][3]));
#pragma unroll
        for (int nt = 1; nt < 4; nt++)
            mt = fmaxf(mt, fmaxf(fmaxf(s[nt][0], s[nt][1]), fmaxf(s[nt][2], s[nt][3])));
        mt = fmaxf(mt, __shfl_xor(mt, 16));
        mt = fmaxf(mt, __shfl_xor(mt, 32));
        if (!__all(mt - m_run <= 8.0f)) {
            float mn = fmaxf(m_run, mt);
            float sc = exp2f(m_run - mn);
            l_run *= sc;
            float scr[4];
#pragma unroll
            for (int reg = 0; reg < 4; reg++) scr[reg] = __shfl(sc, lhi * 4 + reg);
#pragma unroll
            for (int dt = 0; dt < 4; dt++)
#pragma unroll
                for (int reg = 0; reg < 4; reg++) acc[dt][reg] *= scr[reg];
            m_run = mn;
        }
        float ps = 0.f;
#pragma unroll
        for (int nt = 0; nt < 4; nt++)
#pragma unroll
            for (int reg = 0; reg < 4; reg++) {
                float p = exp2f(s[nt][reg] - m_run);
                s[nt][reg] = p;
                ps += p;
            }
        ps += __shfl_xor(ps, 16);
        ps += __shfl_xor(ps, 32);
        l_run += ps;

        // ---- P -> wave-private LDS bridge: 4 consecutive k per write ----
        char* pl = (char*)P_lds[wave];
        const int rs = (l15 & 7) << 4;
#pragma unroll
        for (int nt = 0; nt < 4; nt++) {
            bf16x4 pw;
#pragma unroll
            for (int reg = 0; reg < 4; reg++) pw[reg] = (__bf16)s[nt][reg];
            *(bf16x4*)(pl + ((l15 * 128 + (nt * 16 + lhi * 4) * 2) ^ rs)) = pw;
        }

        // ---- O += P V ----
        __builtin_amdgcn_s_setprio(1);
#pragma unroll
        for (int kc = 0; kc < 2; kc++) {
            const bf16x8 pfg = *(const bf16x8*)(pl +
                ((l15 * 128 + kc * 64 + lhi * 16) ^ rs));
#pragma unroll
            for (int dt = 0; dt < 4; dt++) {
                int drow = dt * 16 + l15;
                const bf16x8 vf = *(const bf16x8*)(Vb +
                    ((drow * 128 + kc * 64 + lhi * 16) ^ VSWZ(drow)));
                acc[dt] = __builtin_amdgcn_mfma_f32_16x16x32_bf16(pfg, vf, acc[dt], 0, 0, 0);
            }
        }
        __builtin_amdgcn_s_setprio(0);

        if (pf) STORE_TILE(bufi ^ 1);          // publish next tile
        __syncthreads();
        bufi ^= 1;
    }

    if (direct) {
        // ---- normalize + scatter + fused zero rows ----
        float lq[4];
#pragma unroll
        for (int reg = 0; reg < 4; reg++) lq[reg] = __shfl(l_run, lhi * 4 + reg);
#pragma unroll
        for (int reg = 0; reg < 4; reg++) {
            float inv = 1.0f / lq[reg];
            int qr = qrow_base + lhi * 4 + reg;
            long tok = sstart + off + (long)r * qr;
            float* op = Og + tok * 768 + head * 64 + l15;
#pragma unroll
            for (int dt = 0; dt < 4; dt++) op[dt * 16] = acc[dt][reg] * inv;
            if (r >= 2) {
                float* z1 = op - 768;
#pragma unroll
                for (int dt = 0; dt < 4; dt++) z1[dt * 16] = 0.f;
            }
            if (r == 4) {
                float* z2 = op - 2 * 768;
                float* z3 = op + 768;
#pragma unroll
                for (int dt = 0; dt < 4; dt++) { z2[dt * 16] = 0.f; z3[dt * 16] = 0.f; }
            }
        }
    } else {
        // ---- write unnormalized partial to ws slot (bf16 O, f32 m/l) ----
        const int b  = (qt < 8)  ? (qt - 4) * 2
                     : (qt < 12) ? 8 + (qt - 8) * 3
                     :             20 + (qt - 12) * 4;
        char* slotp = ws + (size_t)(inst * 36 + b + c) * 17408;
        __bf16* so = (__bf16*)slotp;
#pragma unroll
        for (int reg = 0; reg < 4; reg++) {
            int row = wave * 16 + lhi * 4 + reg;
#pragma unroll
            for (int dt = 0; dt < 4; dt++)
                so[row * 64 + dt * 16 + l15] = (__bf16)acc[dt][reg];
        }
        if (lhi == 0) {                         // lane owns q = l15
            float* ml = (float*)(slotp + 16384);
            ml[wave * 16 + l15]       = m_run;
            ml[128 + wave * 16 + l15] = l_run;
        }
    }
#undef LOAD_TILE
#undef STORE_TILE
}

__global__ __launch_bounds__(256)
void dilattn_merge(const char* __restrict__ ws, float* __restrict__ Og,
                   const int* __restrict__ causal_p)
{
    if (!*causal_p) return;                    // non-causal handled directly
    const int bid  = blockIdx.x;
    const int inst = bid / 12;
    const int qt   = 4 + bid % 12;
    int head, sstart, r, off;
    inst_decode(inst, head, sstart, r, off);

    const int nc = (2 * qt + 9) >> 3;          // chunks: 2..4
    const int b  = (qt < 8)  ? (qt - 4) * 2
                 : (qt < 12) ? 8 + (qt - 8) * 3
                 :             20 + (qt - 12) * 4;
    const char* base = ws + (size_t)(inst * 36 + b) * 17408;

    const int tid = threadIdx.x;
    const int row = tid >> 1;                  // 0..127
    const int c32 = (tid & 1) * 32;

    float mv[4], lv[4];
    float m = -INFINITY;
#pragma unroll
    for (int c = 0; c < 4; c++) {
        if (c < nc) {
            const float* ml = (const float*)(base + c * 17408 + 16384);
            mv[c] = ml[row];
            lv[c] = ml[128 + row];
            m = fmaxf(m, mv[c]);
        }
    }
    float w[4];
    float L = 0.f;
#pragma unroll
    for (int c = 0; c < 4; c++) {
        if (c < nc) {
            w[c] = exp2f(mv[c] - m);
            L += w[c] * lv[c];
        }
    }
    const float invL = 1.0f / L;

    f32x4 o[8] = {};
#pragma unroll
    for (int c = 0; c < 4; c++) {
        if (c < nc) {
            const __bf16* ob = (const __bf16*)(base + c * 17408) + row * 64 + c32;
#pragma unroll
            for (int j = 0; j < 4; j++) {
                bf16x8 t = *(const bf16x8*)(ob + j * 8);
#pragma unroll
                for (int e = 0; e < 4; e++) {
                    o[j * 2][e]     += w[c] * (float)t[e];
                    o[j * 2 + 1][e] += w[c] * (float)t[4 + e];
                }
            }
        }
    }

    long tok = sstart + off + (long)r * (qt * 128 + row);
    float* og = Og + tok * 768 + head * 64 + c32;
#pragma unroll
    for (int j = 0; j < 8; j++) {
        f32x4 t;
#pragma unroll
        for (int e = 0; e < 4; e++) t[e] = o[j][e] * invL;
        *(f32x4*)(og + j * 4) = t;
    }
    // ---- fused zero rows for non-dilated tokens ----
    const f32x4 zz = {};
    if (r >= 2) {
        float* z1 = og - 768;
#pragma unroll
        for (int j = 0; j < 8; j++) *(f32x4*)(z1 + j * 4) = zz;
    }
    if (r == 4) {
        float* z2 = og - 2 * 768;
        float* z3 = og + 768;
#pragma unroll
        for (int j = 0; j < 8; j++) { *(f32x4*)(z2 + j * 4) = zz; *(f32x4*)(z3 + j * 4) = zz; }
    }
}

extern "C" void kernel_launch(void* const* d_in, const int* in_sizes, int n_in,
                              void* d_out, int out_size, void* d_ws, size_t ws_size,
                              hipStream_t stream)
{
    const float* q = (const float*)d_in[0];
    const float* k = (const float*)d_in[1];
    const float* v = (const float*)d_in[2];
    const int* causal = (const int*)d_in[3];
    float* out = (float*)d_out;
    char* ws   = (char*)d_ws;

    dilattn_partial<<<dim3(28 * 40), dim3(512), 0, stream>>>(q, k, v, out, ws, causal);
    dilattn_merge<<<dim3(28 * 12), dim3(256), 0, stream>>>(ws, out, causal);
}

// Round 9
// 68.858 us; speedup vs baseline: 6.1117x; 1.0101x over previous
//
#include <hip/hip_runtime.h>

typedef __attribute__((ext_vector_type(8))) __bf16 bf16x8;
typedef __attribute__((ext_vector_type(4))) __bf16 bf16x4;
typedef __attribute__((ext_vector_type(2))) __bf16 bf16x2;
typedef __attribute__((ext_vector_type(4))) float f32x4;

#define LOG2E 1.44269504088896f
#define KSWZ(t) (((t) & 7) << 4)
#define VSWZ(d) ((((d) & 7) ^ (((d) >> 3) & 7)) << 4)

// 28 instances of dilated causal attention, each L=2048, d=64.
// q/k/v: (1, 8192, 12, 64) fp32 -> elem = tok*768 + head*64 + d.
// QBLK=128 (8 waves x 16 q-rows), KV tile 64, chunks of <=8 KV tiles:
// 40 units/inst -> 1120 blocks, XCD-chunked, heavy-first.
// Wave-specialized staging (waves 0-3: K, 4-7: V^T), swapped QK^T ->
// in-register softmax, defer-max (THR=8, log2 domain).
// R9: SINGLE KV buffer (16K) + P bridge (16K) = 32 KB -> 4 blocks/CU
// (was 48 KB / 3 blocks): occupancy was the binding constraint (29%,
// ~2.3 waves/SIMD, latency-stalled). Register prefetch of tile t+1 still
// hides HBM latency; extra barrier per tile is the price.
// Two kernels, NO device fences (R7 lesson: in-kernel cross-XCD fences
// stall the grid ~7x; kernel boundary gives visibility for free).
// Output zeroing for non-dilated rows fused into epilogues (no memset).
// ws slot (17408 B): O[128][64] bf16 (16384) + m[128] f32 + l[128] f32.
// slot index = inst*36 + b + c.

__device__ __forceinline__ void inst_decode(int inst, int& head, int& sstart,
                                            int& r, int& off)
{
    if (inst < 16)      { head = inst & 3;          sstart = (inst >> 2) * 2048; r = 1; off = 0; }
    else if (inst < 24) { int j = inst - 16; head = 4 + (j & 3); sstart = (j >> 2) * 4096; r = 2; off = 1; }
    else                { head = 8 + (inst - 24);   sstart = 0;                  r = 4; off = 2; }
}

__global__ __launch_bounds__(512)
void dilattn_partial(const float* __restrict__ Qg, const float* __restrict__ Kg,
                     const float* __restrict__ Vg, float* __restrict__ Og,
                     char* __restrict__ ws, const int* __restrict__ causal_p)
{
    const int bid  = blockIdx.x;
    const int unit = (bid & 7) * 140 + (bid >> 3);   // XCD-contiguous units
    const int inst = unit / 40;
    const int u    = 39 - (unit % 40);               // heavy chunks first
    int qt, c;
    if (u < 4) { qt = u; c = 0; }
    else {
        int v = u - 4;
        if (v < 8)       { qt = 4 + (v >> 1); c = v & 1; }
        else if (v < 20) { int t = v - 8; int q3 = t / 3; qt = 8 + q3; c = t - 3 * q3; }
        else             { int t = v - 20; qt = 12 + (t >> 2); c = t & 3; }
    }
    int head, sstart, r, off;
    inst_decode(inst, head, sstart, r, off);

    const int causal = *causal_p;
    int kt_begin, kt_end;
    bool direct;
    if (causal) {
        int nkt = 2 * qt + 2;
        kt_begin = c * 8;
        kt_end   = (kt_begin + 8 < nkt) ? kt_begin + 8 : nkt;
        direct   = (qt < 4);
    } else {
        if (c) return;
        kt_begin = 0; kt_end = 32; direct = true;
    }

    const int tid  = threadIdx.x;
    const int lane = tid & 63;
    const int wave = tid >> 6;                 // 0..7
    const int l15  = lane & 15;
    const int lhi  = lane >> 4;

    __shared__ char KV[16384];                 // K 8K | V^T 8K (single buffer)
    __shared__ __bf16 P_lds[8][16 * 64];       // per-wave P bridge (swizzled)

    // ---- Q fragments (scale * log2e folded in); serves as MFMA B ----
    const int qrow_base = qt * 128 + wave * 16;
    const float qscale = 0.125f * LOG2E;
    bf16x8 qfrag[2];
    {
        int qr = qrow_base + l15;
        long qtok = sstart + off + (long)r * qr;
        const float* qp = Qg + qtok * 768 + head * 64 + lhi * 8;
#pragma unroll
        for (int dc = 0; dc < 2; dc++) {
            f32x4 a = *(const f32x4*)(qp + dc * 32);
            f32x4 b = *(const f32x4*)(qp + dc * 32 + 4);
#pragma unroll
            for (int j = 0; j < 4; j++) {
                qfrag[dc][j]     = (__bf16)(a[j] * qscale);
                qfrag[dc][4 + j] = (__bf16)(b[j] * qscale);
            }
        }
    }

    f32x4 acc[4] = {};                          // O: row q=lhi*4+reg, col d=dt*16+l15
    float m_run = -INFINITY;                    // per-lane: q = l15
    float l_run = 0.f;

    // ---- wave-specialized staging roles ----
    const bool isK = (wave < 4);
    const int t2   = tid & 255;
    const int tokK = t2 >> 2, q4 = t2 & 3;          // K: (token, d-quarter)
    const int tokP = t2 >> 3, d8 = (t2 & 7) * 8;    // V: (token-pair, 8 d)

    f32x4 r0, r1, r2, r3;                       // staging regs (next tile)

#define LOAD_TILE(KT) do {                                                     \
        long tb = sstart + off + (long)r * ((KT) * 64);                        \
        if (isK) {                                                             \
            const float* p_ = Kg + (tb + (long)r * tokK) * 768 + head * 64 + q4 * 16; \
            r0 = *(const f32x4*)(p_);      r1 = *(const f32x4*)(p_ + 4);       \
            r2 = *(const f32x4*)(p_ + 8);  r3 = *(const f32x4*)(p_ + 12);      \
        } else {                                                               \
            const float* p0_ = Vg + (tb + (long)r * 2 * tokP) * 768 + head * 64 + d8; \
            const float* p1_ = p0_ + (long)r * 768;                            \
            r0 = *(const f32x4*)(p0_);     r1 = *(const f32x4*)(p0_ + 4);      \
            r2 = *(const f32x4*)(p1_);     r3 = *(const f32x4*)(p1_ + 4);      \
        }                                                                      \
    } while (0)

#define STORE_TILE() do {                                                      \
        if (isK) {                                                             \
            char* Kb_ = KV;                                                    \
            bf16x8 w0_, w1_;                                                   \
            _Pragma("unroll")                                                  \
            for (int j = 0; j < 4; j++) {                                      \
                w0_[j] = (__bf16)r0[j]; w0_[4 + j] = (__bf16)r1[j];            \
                w1_[j] = (__bf16)r2[j]; w1_[4 + j] = (__bf16)r3[j];            \
            }                                                                  \
            int kb_ = tokK * 128 + q4 * 32;                                    \
            *(bf16x8*)(Kb_ + ((kb_)      ^ KSWZ(tokK))) = w0_;                 \
            *(bf16x8*)(Kb_ + ((kb_ + 16) ^ KSWZ(tokK))) = w1_;                 \
        } else {                                                               \
            char* Vb_ = KV + 8192;                                             \
            _Pragma("unroll")                                                  \
            for (int j = 0; j < 4; j++) {                                      \
                int d_ = d8 + j;                                               \
                bf16x2 wa_; wa_[0] = (__bf16)r0[j]; wa_[1] = (__bf16)r2[j];    \
                *(bf16x2*)(Vb_ + ((d_ * 128 + tokP * 4) ^ VSWZ(d_))) = wa_;    \
                int d2_ = d8 + 4 + j;                                          \
                bf16x2 wb_; wb_[0] = (__bf16)r1[j]; wb_[1] = (__bf16)r3[j];    \
                *(bf16x2*)(Vb_ + ((d2_ * 128 + tokP * 4) ^ VSWZ(d2_))) = wb_;  \
            }                                                                  \
        }                                                                      \
    } while (0)

    // ---- prologue: stage first tile ----
    LOAD_TILE(kt_begin);
    STORE_TILE();
    __syncthreads();

    for (int kt = kt_begin; kt < kt_end; kt++) {
        const bool pf = (kt + 1 < kt_end);
        if (pf) LOAD_TILE(kt + 1);             // issue early; lands under compute

        char* Kb = KV;
        char* Vb = KV + 8192;

        // ---- S' = K Q^T : lane owns q = l15; regs (nt,reg) = k values ----
        f32x4 s[4];
        __builtin_amdgcn_s_setprio(1);
#pragma unroll
        for (int nt = 0; nt < 4; nt++) {
            f32x4 cc = {};
#pragma unroll
            for (int dc = 0; dc < 2; dc++) {
                int krow = nt * 16 + l15;
                const bf16x8 kf = *(const bf16x8*)(Kb +
                    ((krow * 128 + dc * 64 + lhi * 16) ^ KSWZ(krow)));
                cc = __builtin_amdgcn_mfma_f32_16x16x32_bf16(kf, qfrag[dc], cc, 0, 0, 0);
            }
            s[nt] = cc;
        }
        __builtin_amdgcn_s_setprio(0);

        // ---- causal mask: tiles kt = 2qt, 2qt+1 overlap the diagonal ----
        if (causal && (kt >> 1) == qt) {
            const int kofs = kt * 64 - qt * 128 - wave * 16;  // k_local - q base
#pragma unroll
            for (int nt = 0; nt < 4; nt++)
#pragma unroll
                for (int reg = 0; reg < 4; reg++)
                    if (kofs + nt * 16 + lhi * 4 + reg > l15)
                        s[nt][reg] = -INFINITY;
        }

        // ---- in-register online softmax with defer-max (THR=8, log2) ----
        float mt = fmaxf(fmaxf(s[0][0], s[0][1]), fmaxf(s[0][2], s[0][3]));
#pragma unroll
        for (int nt = 1; nt < 4; nt++)
            mt = fmaxf(mt, fmaxf(fmaxf(s[nt][0], s[nt][1]), fmaxf(s[nt][2], s[nt][3])));
        mt = fmaxf(mt, __shfl_xor(mt, 16));
        mt = fmaxf(mt, __shfl_xor(mt, 32));
        if (!__all(mt - m_run <= 8.0f)) {
            float mn = fmaxf(m_run, mt);
            float sc = exp2f(m_run - mn);
            l_run *= sc;
            float scr[4];
#pragma unroll
            for (int reg = 0; reg < 4; reg++) scr[reg] = __shfl(sc, lhi * 4 + reg);
#pragma unroll
            for (int dt = 0; dt < 4; dt++)
#pragma unroll
                for (int reg = 0; reg < 4; reg++) acc[dt][reg] *= scr[reg];
            m_run = mn;
        }
        float ps = 0.f;
#pragma unroll
        for (int nt = 0; nt < 4; nt++)
#pragma unroll
            for (int reg = 0; reg < 4; reg++) {
                float p = exp2f(s[nt][reg] - m_run);
                s[nt][reg] = p;
                ps += p;
            }
        ps += __shfl_xor(ps, 16);
        ps += __shfl_xor(ps, 32);
        l_run += ps;

        // ---- P -> wave-private LDS bridge: 4 consecutive k per write ----
        char* pl = (char*)P_lds[wave];
        const int rs = (l15 & 7) << 4;
#pragma unroll
        for (int nt = 0; nt < 4; nt++) {
            bf16x4 pw;
#pragma unroll
            for (int reg = 0; reg < 4; reg++) pw[reg] = (__bf16)s[nt][reg];
            *(bf16x4*)(pl + ((l15 * 128 + (nt * 16 + lhi * 4) * 2) ^ rs)) = pw;
        }

        // ---- O += P V ----
        __builtin_amdgcn_s_setprio(1);
#pragma unroll
        for (int kc = 0; kc < 2; kc++) {
            const bf16x8 pfg = *(const bf16x8*)(pl +
                ((l15 * 128 + kc * 64 + lhi * 16) ^ rs));
#pragma unroll
            for (int dt = 0; dt < 4; dt++) {
                int drow = dt * 16 + l15;
                const bf16x8 vf = *(const bf16x8*)(Vb +
                    ((drow * 128 + kc * 64 + lhi * 16) ^ VSWZ(drow)));
                acc[dt] = __builtin_amdgcn_mfma_f32_16x16x32_bf16(pfg, vf, acc[dt], 0, 0, 0);
            }
        }
        __builtin_amdgcn_s_setprio(0);

        __syncthreads();                       // all reads of KV done
        if (pf) {
            STORE_TILE();                      // overwrite with tile kt+1
            __syncthreads();                   // staged
        }
    }

    if (direct) {
        // ---- normalize + scatter + fused zero rows ----
        float lq[4];
#pragma unroll
        for (int reg = 0; reg < 4; reg++) lq[reg] = __shfl(l_run, lhi * 4 + reg);
#pragma unroll
        for (int reg = 0; reg < 4; reg++) {
            float inv = 1.0f / lq[reg];
            int qr = qrow_base + lhi * 4 + reg;
            long tok = sstart + off + (long)r * qr;
            float* op = Og + tok * 768 + head * 64 + l15;
#pragma unroll
            for (int dt = 0; dt < 4; dt++) op[dt * 16] = acc[dt][reg] * inv;
            if (r >= 2) {
                float* z1 = op - 768;
#pragma unroll
                for (int dt = 0; dt < 4; dt++) z1[dt * 16] = 0.f;
            }
            if (r == 4) {
                float* z2 = op - 2 * 768;
                float* z3 = op + 768;
#pragma unroll
                for (int dt = 0; dt < 4; dt++) { z2[dt * 16] = 0.f; z3[dt * 16] = 0.f; }
            }
        }
    } else {
        // ---- write unnormalized partial to ws slot (bf16 O, f32 m/l) ----
        const int b  = (qt < 8)  ? (qt - 4) * 2
                     : (qt < 12) ? 8 + (qt - 8) * 3
                     :             20 + (qt - 12) * 4;
        char* slotp = ws + (size_t)(inst * 36 + b + c) * 17408;
        __bf16* so = (__bf16*)slotp;
#pragma unroll
        for (int reg = 0; reg < 4; reg++) {
            int row = wave * 16 + lhi * 4 + reg;
#pragma unroll
            for (int dt = 0; dt < 4; dt++)
                so[row * 64 + dt * 16 + l15] = (__bf16)acc[dt][reg];
        }
        if (lhi == 0) {                         // lane owns q = l15
            float* ml = (float*)(slotp + 16384);
            ml[wave * 16 + l15]       = m_run;
            ml[128 + wave * 16 + l15] = l_run;
        }
    }
#undef LOAD_TILE
#undef STORE_TILE
}

__global__ __launch_bounds__(256)
void dilattn_merge(const char* __restrict__ ws, float* __restrict__ Og,
                   const int* __restrict__ causal_p)
{
    if (!*causal_p) return;                    // non-causal handled directly
    const int bid  = blockIdx.x;
    const int inst = bid / 12;
    const int qt   = 4 + bid % 12;
    int head, sstart, r, off;
    inst_decode(inst, head, sstart, r, off);

    const int nc = (2 * qt + 9) >> 3;          // chunks: 2..4
    const int b  = (qt < 8)  ? (qt - 4) * 2
                 : (qt < 12) ? 8 + (qt - 8) * 3
                 :             20 + (qt - 12) * 4;
    const char* base = ws + (size_t)(inst * 36 + b) * 17408;

    const int tid = threadIdx.x;
    const int row = tid >> 1;                  // 0..127
    const int c32 = (tid & 1) * 32;

    float mv[4], lv[4];
    float m = -INFINITY;
#pragma unroll
    for (int c = 0; c < 4; c++) {
        if (c < nc) {
            const float* ml = (const float*)(base + c * 17408 + 16384);
            mv[c] = ml[row];
            lv[c] = ml[128 + row];
            m = fmaxf(m, mv[c]);
        }
    }
    float w[4];
    float L = 0.f;
#pragma unroll
    for (int c = 0; c < 4; c++) {
        if (c < nc) {
            w[c] = exp2f(mv[c] - m);
            L += w[c] * lv[c];
        }
    }
    const float invL = 1.0f / L;

    f32x4 o[8] = {};
#pragma unroll
    for (int c = 0; c < 4; c++) {
        if (c < nc) {
            const __bf16* ob = (const __bf16*)(base + c * 17408) + row * 64 + c32;
#pragma unroll
            for (int j = 0; j < 4; j++) {
                bf16x8 t = *(const bf16x8*)(ob + j * 8);
#pragma unroll
                for (int e = 0; e < 4; e++) {
                    o[j * 2][e]     += w[c] * (float)t[e];
                    o[j * 2 + 1][e] += w[c] * (float)t[4 + e];
                }
            }
        }
    }

    long tok = sstart + off + (long)r * (qt * 128 + row);
    float* og = Og + tok * 768 + head * 64 + c32;
#pragma unroll
    for (int j = 0; j < 8; j++) {
        f32x4 t;
#pragma unroll
        for (int e = 0; e < 4; e++) t[e] = o[j][e] * invL;
        *(f32x4*)(og + j * 4) = t;
    }
    // ---- fused zero rows for non-dilated tokens ----
    const f32x4 zz = {};
    if (r >= 2) {
        float* z1 = og - 768;
#pragma unroll
        for (int j = 0; j < 8; j++) *(f32x4*)(z1 + j * 4) = zz;
    }
    if (r == 4) {
        float* z2 = og - 2 * 768;
        float* z3 = og + 768;
#pragma unroll
        for (int j = 0; j < 8; j++) { *(f32x4*)(z2 + j * 4) = zz; *(f32x4*)(z3 + j * 4) = zz; }
    }
}

extern "C" void kernel_launch(void* const* d_in, const int* in_sizes, int n_in,
                              void* d_out, int out_size, void* d_ws, size_t ws_size,
                              hipStream_t stream)
{
    const float* q = (const float*)d_in[0];
    const float* k = (const float*)d_in[1];
    const float* v = (const float*)d_in[2];
    const int* causal = (const int*)d_in[3];
    float* out = (float*)d_out;
    char* ws   = (char*)d_ws;

    dilattn_partial<<<dim3(28 * 40), dim3(512), 0, stream>>>(q, k, v, out, ws, causal);
    dilattn_merge<<<dim3(28 * 12), dim3(256), 0, stream>>>(ws, out, causal);
}